// Round 23
// baseline (134.962 us; speedup 1.0000x reference)
//
#include <hip/hip_runtime.h>
#include <hip/hip_bf16.h>
#include <hip/hip_fp16.h>
#include <math.h>

#define NN 64000      // nodes
#define NE 1024000    // edges
#define NB 4000       // sequences
#define NT 16         // timesteps
#define LROWS 16      // sequences per LSTM block
#define NBKT 250      // coarse buckets (c>>8), NN/256
#define BSTRIDE 5120  // fixed per-bucket slot region (mean 4096, sigma 64 -> 16-sigma margin)

typedef __attribute__((ext_vector_type(8))) short short8;
typedef __attribute__((ext_vector_type(4))) float f32x4;

// fast sigmoid/tanh: v_exp + v_rcp (exact at +-inf limits)
__device__ __forceinline__ float fsigm(float x) {
    return __builtin_amdgcn_rcpf(1.0f + __expf(-x));
}
__device__ __forceinline__ float ftanh(float x) {
    return 1.0f - 2.0f * __builtin_amdgcn_rcpf(1.0f + __expf(2.0f * x));
}
__device__ __forceinline__ unsigned short hbits(float v) {
    __half h = __float2half(v);
    return reinterpret_cast<unsigned short&>(h);
}
__device__ __forceinline__ float hval(unsigned short b) {
    __half h;
    reinterpret_cast<unsigned short&>(h) = b;
    return __half2float(h);
}

// ---------- P1: bin edges by bucket via LDS sort; direct atomic slot reservation ----------
// recA: r | (c&255)<<16 | bucket<<24 ; recW: f16 weight bits (dinv from f16: +2.5e-4 rel, safe)
__global__ __launch_bounds__(256) void k_bin(const int* __restrict__ ei,
                                             const float* __restrict__ ew,
                                             int* __restrict__ bcur,
                                             unsigned* __restrict__ binnedA,
                                             unsigned short* __restrict__ binnedW) {
    __shared__ unsigned stageA[4096];
    __shared__ unsigned short stageW[4096];
    __shared__ int sm[256];
    __shared__ int lcur[256], ladj[256];
    int tid = threadIdx.x;
    sm[tid] = 0;
    __syncthreads();
    int base = blockIdx.x * 4096;
    int cs[16];
    #pragma unroll
    for (int j = 0; j < 16; ++j) {
        cs[j] = ei[NE + base + j * 256 + tid];
        atomicAdd(&sm[cs[j] >> 8], 1);
    }
    __syncthreads();
    int v = sm[tid];
    #pragma unroll
    for (int d = 1; d < 256; d <<= 1) {
        int t = (tid >= d) ? sm[tid - d] : 0;
        __syncthreads();
        sm[tid] += t;
        __syncthreads();
    }
    int ex = sm[tid] - v;
    lcur[tid] = ex;
    if (tid < NBKT) ladj[tid] = tid * BSTRIDE + atomicAdd(&bcur[tid], v) - ex;
    __syncthreads();
    #pragma unroll
    for (int j = 0; j < 16; ++j) {
        int e = base + j * 256 + tid;
        int c = cs[j];
        int b = c >> 8;
        unsigned r = (unsigned)ei[e];
        float wv = ew[e];
        int slot = atomicAdd(&lcur[b], 1);
        stageA[slot] = r | ((unsigned)(c & 255) << 16) | ((unsigned)b << 24);
        stageW[slot] = hbits(wv);
    }
    __syncthreads();
    #pragma unroll
    for (int j = 0; j < 16; ++j) {
        int i = j * 256 + tid;
        unsigned recA = stageA[i];
        int b = recA >> 24;
        int dst = ladj[b] + i;
        binnedA[dst] = recA;
        binnedW[dst] = stageW[i];
    }
}

// ---------- P2: per-bucket final CSR sort + offS/offE + dinv + fused xh ----------
// edata packed 4B: r (low16) | f16(w) (high16); strided bucket regions
__global__ __launch_bounds__(256) void k_csr(const unsigned* __restrict__ binnedA,
                                             const unsigned short* __restrict__ binnedW,
                                             const int* __restrict__ bcur,
                                             const float* __restrict__ x,
                                             unsigned* __restrict__ edata,
                                             int* __restrict__ offS,
                                             int* __restrict__ offE,
                                             float* __restrict__ dinv,
                                             __half* __restrict__ xh) {
    __shared__ int cnt[256];
    __shared__ float sumw[256];
    __shared__ int lcur[256];
    __shared__ int sm[256];
    int tid = threadIdx.x;
    int b = blockIdx.x;
    int s = b * BSTRIDE;
    int e1 = s + bcur[b];
    cnt[tid] = 0;
    sumw[tid] = 0.0f;
    __syncthreads();
    for (int i = s + tid; i < e1; i += 256) {
        unsigned recA = binnedA[i];
        int nl = (recA >> 16) & 255;
        atomicAdd(&cnt[nl], 1);
        atomicAdd(&sumw[nl], hval(binnedW[i]));
    }
    __syncthreads();
    int v = cnt[tid];
    sm[tid] = v;
    __syncthreads();
    #pragma unroll
    for (int d = 1; d < 256; d <<= 1) {
        int t = (tid >= d) ? sm[tid - d] : 0;
        __syncthreads();
        sm[tid] += t;
        __syncthreads();
    }
    int ex = sm[tid] - v;
    offS[b * 256 + tid] = s + ex;
    offE[b * 256 + tid] = s + ex + v;
    float dv = rsqrtf(1.0f + sumw[tid]);
    dinv[b * 256 + tid] = dv;
    sumw[tid] = dv;           // stash for xh loop
    lcur[tid] = ex;
    __syncthreads();
    for (int i = s + tid; i < e1; i += 256) {
        unsigned recA = binnedA[i];
        int nl = (recA >> 16) & 255;
        int p = atomicAdd(&lcur[nl], 1);
        edata[s + p] = (recA & 0xFFFFu) | ((unsigned)binnedW[i] << 16);
    }
    // fused xh = x * dinv for this block's 256 nodes
    size_t nb = (size_t)b * 4096;
    for (int i = tid; i < 4096; i += 256) {
        xh[nb + i] = __float2half(x[nb + i] * sumw[i >> 4]);
    }
}

// ---------- gather on 16-feature xh: aggx[n] = f16( dinv[n]*(xh[n] + sum ew*xh[r]) ) ----------
__global__ __launch_bounds__(256) void k_gather16(const __half* __restrict__ xh,
                                                  const unsigned* __restrict__ edata,
                                                  const int* __restrict__ offS,
                                                  const int* __restrict__ offE,
                                                  const float* __restrict__ dinv,
                                                  __half* __restrict__ aggx) {
    int tid = threadIdx.x;
    int lane = tid & 63;
    int wv = tid >> 6;
    int n = blockIdx.x * 4 + wv;
    int g = lane >> 3;        // edge group 0..7
    int fl = lane & 7;        // feature-pair 0..7
    const __half2* xh2 = (const __half2*)xh;   // row stride 8 half2
    float2 acc = make_float2(0.0f, 0.0f);
    if (g == 0) acc = __half22float2(xh2[((size_t)n << 3) + fl]);   // self term
    int s = offS[n], e1 = offE[n];
    int e = s + g;
    for (; e + 8 < e1; e += 16) {
        unsigned d0 = edata[e];
        unsigned d1 = edata[e + 8];
        float2 l0 = __half22float2(xh2[((size_t)(d0 & 0xFFFFu) << 3) + fl]);
        float2 l1 = __half22float2(xh2[((size_t)(d1 & 0xFFFFu) << 3) + fl]);
        float w0 = hval((unsigned short)(d0 >> 16));
        float w1 = hval((unsigned short)(d1 >> 16));
        acc.x = fmaf(w0, l0.x, acc.x); acc.y = fmaf(w0, l0.y, acc.y);
        acc.x = fmaf(w1, l1.x, acc.x); acc.y = fmaf(w1, l1.y, acc.y);
    }
    if (e < e1) {
        unsigned d0 = edata[e];
        float2 l0 = __half22float2(xh2[((size_t)(d0 & 0xFFFFu) << 3) + fl]);
        float w0 = hval((unsigned short)(d0 >> 16));
        acc.x = fmaf(w0, l0.x, acc.x);
        acc.y = fmaf(w0, l0.y, acc.y);
    }
    acc.x += __shfl_xor(acc.x, 8, 64);
    acc.y += __shfl_xor(acc.y, 8, 64);
    acc.x += __shfl_xor(acc.x, 16, 64);
    acc.y += __shfl_xor(acc.y, 16, 64);
    acc.x += __shfl_xor(acc.x, 32, 64);
    acc.y += __shfl_xor(acc.y, 32, 64);
    if (g == 0) {
        float dn = dinv[n];
        ((__half2*)aggx)[((size_t)n << 3) + fl] = __floats2half2_rn(dn * acc.x, dn * acc.y);
    }
}

// ---------- fused weight fragments + bcur zero ----------
// blocks 0..383: LSTM f16 frags; block 384: GCN frags; block 385: zero bcur
__global__ __launch_bounds__(256) void k_wfrag(const float* __restrict__ W_ih,
                                               const float* __restrict__ W_hh,
                                               const float* __restrict__ b_ih,
                                               const float* __restrict__ b_hh,
                                               const float* __restrict__ W1,
                                               const float* __restrict__ W2,
                                               unsigned short* __restrict__ Bus,
                                               float* __restrict__ biasb,
                                               unsigned short* __restrict__ W1f,
                                               unsigned short* __restrict__ W2f,
                                               int* __restrict__ bcur) {
    int tid = threadIdx.x;
    int blk = blockIdx.x;
    if (blk < 384) {
        int i = blk * 256 + tid;
        if (i < 192 * 512) {
            int j = i & 7;
            int l = (i >> 3) & 63;
            int ci = i >> 9;
            int ntg = ci & 31;
            int ks = ci >> 5;
            int col = ntg * 16 + (l & 15);
            int k = ks * 32 + ((l >> 4) << 3) + j;
            float w = (k < 64) ? W_ih[col * 64 + k] : W_hh[col * 128 + (k - 64)];
            Bus[i] = hbits(w);
        }
        if (i < 512) biasb[i] = b_ih[i] + b_hh[i];
    } else if (blk == 384) {
        for (int i = tid; i < 6144; i += 256) {
            if (i < 2048) {
                int j = i & 7, l = (i >> 3) & 63, nt = i >> 9;
                int n = nt * 16 + (l & 15);
                int k = ((l >> 4) << 3) + j;          // 0..31
                W1f[i] = (k < 16) ? hbits(W1[k * 64 + n]) : (unsigned short)0;
            } else {
                int i2 = i - 2048;
                int j = i2 & 7, l = (i2 >> 3) & 63, ci = i2 >> 9;
                int nt = ci & 3, ks = ci >> 2;
                int n = nt * 16 + (l & 15);
                int k = ks * 32 + ((l >> 4) << 3) + j;
                W2f[i2] = hbits(W2[k * 64 + n]);
            }
        }
    } else {
        bcur[tid] = 0;
    }
}

// ---------- fused deferred-W1 + layer-2 lin via MFMA ----------
// 64 rows/block, 4 waves. hid = relu(aggx@W1 + b1); linp2 = (hid@W2)*dinv -> fp16
__global__ __launch_bounds__(256) void k_lin2f(const __half* __restrict__ aggx,
                                               const unsigned short* __restrict__ W1f,
                                               const float* __restrict__ b1,
                                               const unsigned short* __restrict__ W2f,
                                               const float* __restrict__ dinv,
                                               __half* __restrict__ linp2) {
    __shared__ unsigned short Ax[4][512];      // GEMM1 A-frags, per wave
    __shared__ unsigned short Hd[4][2][512];   // hid A-frags (K=64 -> 2 chunks), per wave
    __shared__ unsigned short Ot[64 * 64];     // output staging
    int tid = threadIdx.x;
    int lane = tid & 63;
    int w = tid >> 6;
    int n0 = blockIdx.x * 64;

    // B fragments -> registers
    short8 B1[4], B2[8];
    #pragma unroll
    for (int nt = 0; nt < 4; ++nt) B1[nt] = *(const short8*)&W1f[nt * 512 + lane * 8];
    #pragma unroll
    for (int ci = 0; ci < 8; ++ci) B2[ci] = *(const short8*)&W2f[ci * 512 + lane * 8];

    // zero the k>=16 half of each Ax chunk
    {
        int idx = tid;
        ((unsigned int*)Ax)[(idx >> 7) * 256 + 128 + (idx & 127)] = 0;
        idx += 256;
        ((unsigned int*)Ax)[(idx >> 7) * 256 + 128 + (idx & 127)] = 0;
    }
    // stage aggx (f16 bits) -> A-layout: row=tid>>2, k0=(tid&3)*4 (pure bit copy)
    {
        int row = tid >> 2, k0 = (tid & 3) * 4;
        uint2 bits = *(const uint2*)(aggx + (size_t)(n0 + row) * 16 + k0);
        unsigned short hv[4] = {(unsigned short)(bits.x & 0xFFFF), (unsigned short)(bits.x >> 16),
                                (unsigned short)(bits.y & 0xFFFF), (unsigned short)(bits.y >> 16)};
        int wq = row >> 4, m = row & 15;
        #pragma unroll
        for (int d = 0; d < 4; ++d) {
            int k = k0 + d;
            Ax[wq][(((k >> 3) << 4) + m) * 8 + (k & 7)] = hv[d];
        }
    }
    __syncthreads();

    // GEMM1: [16x32(pad)] @ W1 -> 4 N-tiles
    short8 a = *(const short8*)&Ax[w][lane * 8];
    f32x4 acc[4];
    #pragma unroll
    for (int nt = 0; nt < 4; ++nt) acc[nt] = (f32x4){0.f, 0.f, 0.f, 0.f};
    #pragma unroll
    for (int nt = 0; nt < 4; ++nt)
        acc[nt] = __builtin_amdgcn_mfma_f32_16x16x32_f16(a, B1[nt], acc[nt], 0, 0, 0);

    // epilogue 1: relu(acc + b1[col]) -> Hd in GEMM2 A-layout
    int rb = (lane >> 4) * 4;
    #pragma unroll
    for (int nt = 0; nt < 4; ++nt) {
        int col = nt * 16 + (lane & 15);
        float bc = b1[col];
        #pragma unroll
        for (int q = 0; q < 4; ++q) {
            float hv = fmaxf(acc[nt][q] + bc, 0.0f);
            int row = rb + q;
            Hd[w][col >> 5][((((col & 31) >> 3) << 4) + row) * 8 + (col & 7)] = hbits(hv);
        }
    }
    short8 a0 = *(const short8*)&Hd[w][0][lane * 8];
    short8 a1 = *(const short8*)&Hd[w][1][lane * 8];
    f32x4 c2[4];
    #pragma unroll
    for (int nt = 0; nt < 4; ++nt) c2[nt] = (f32x4){0.f, 0.f, 0.f, 0.f};
    #pragma unroll
    for (int nt = 0; nt < 4; ++nt)
        c2[nt] = __builtin_amdgcn_mfma_f32_16x16x32_f16(a0, B2[nt], c2[nt], 0, 0, 0);
    #pragma unroll
    for (int nt = 0; nt < 4; ++nt)
        c2[nt] = __builtin_amdgcn_mfma_f32_16x16x32_f16(a1, B2[4 + nt], c2[nt], 0, 0, 0);

    // epilogue 2: * dinv[row] -> Ot
    float dv[4];
    #pragma unroll
    for (int q = 0; q < 4; ++q) dv[q] = dinv[n0 + w * 16 + rb + q];
    #pragma unroll
    for (int nt = 0; nt < 4; ++nt) {
        int col = nt * 16 + (lane & 15);
        #pragma unroll
        for (int q = 0; q < 4; ++q) {
            Ot[(w * 16 + rb + q) * 64 + col] = hbits(c2[nt][q] * dv[q]);
        }
    }
    __syncthreads();
    {
        int row = tid >> 2, c0 = (tid & 3) * 16;
        short8 v0 = *(const short8*)&Ot[row * 64 + c0];
        short8 v1 = *(const short8*)&Ot[row * 64 + c0 + 8];
        *(short8*)&linp2[(size_t)(n0 + row) * 64 + c0] = v0;
        *(short8*)&linp2[(size_t)(n0 + row) * 64 + c0 + 8] = v1;
    }
}

// ---------- CSR gather, split-wave half2 (layer 2, 64 features) ----------
// output fp16 with relu pre-applied (LSTM staging becomes a bit copy)
__global__ __launch_bounds__(256) void k_gather(const __half* __restrict__ linp,
                                                const unsigned* __restrict__ edata,
                                                const int* __restrict__ offS,
                                                const int* __restrict__ offE,
                                                const float* __restrict__ dinv,
                                                const float* __restrict__ bvec,
                                                __half* __restrict__ agg) {
    int tid = threadIdx.x;
    int lane = tid & 63;
    int wv = tid >> 6;
    int n = blockIdx.x * 4 + wv;
    int hf = lane >> 5;
    int fl = lane & 31;                       // feature-pair index
    const __half2* lp2 = (const __half2*)linp;
    float2 acc = make_float2(0.0f, 0.0f);
    if (hf == 0) {
        acc = __half22float2(lp2[((size_t)n << 5) + fl]);   // self term (once)
    }
    int s = offS[n], e1 = offE[n];
    int e = s + hf;
    for (; e + 6 < e1; e += 8) {
        unsigned d0 = edata[e];
        unsigned d1 = edata[e + 2];
        unsigned d2 = edata[e + 4];
        unsigned d3 = edata[e + 6];
        float2 l0 = __half22float2(lp2[((size_t)(d0 & 0xFFFFu) << 5) + fl]);
        float2 l1 = __half22float2(lp2[((size_t)(d1 & 0xFFFFu) << 5) + fl]);
        float2 l2 = __half22float2(lp2[((size_t)(d2 & 0xFFFFu) << 5) + fl]);
        float2 l3 = __half22float2(lp2[((size_t)(d3 & 0xFFFFu) << 5) + fl]);
        float w0 = hval((unsigned short)(d0 >> 16));
        float w1 = hval((unsigned short)(d1 >> 16));
        float w2 = hval((unsigned short)(d2 >> 16));
        float w3 = hval((unsigned short)(d3 >> 16));
        acc.x = fmaf(w0, l0.x, acc.x); acc.y = fmaf(w0, l0.y, acc.y);
        acc.x = fmaf(w1, l1.x, acc.x); acc.y = fmaf(w1, l1.y, acc.y);
        acc.x = fmaf(w2, l2.x, acc.x); acc.y = fmaf(w2, l2.y, acc.y);
        acc.x = fmaf(w3, l3.x, acc.x); acc.y = fmaf(w3, l3.y, acc.y);
    }
    for (; e < e1; e += 2) {
        unsigned d0 = edata[e];
        float2 l0 = __half22float2(lp2[((size_t)(d0 & 0xFFFFu) << 5) + fl]);
        float w0 = hval((unsigned short)(d0 >> 16));
        acc.x = fmaf(w0, l0.x, acc.x);
        acc.y = fmaf(w0, l0.y, acc.y);
    }
    acc.x += __shfl_xor(acc.x, 32, 64);
    acc.y += __shfl_xor(acc.y, 32, 64);
    if (hf == 0) {
        float dn = dinv[n];
        float ox = fmaxf(fmaf(dn, acc.x, bvec[fl * 2]), 0.0f);
        float oy = fmaxf(fmaf(dn, acc.y, bvec[fl * 2 + 1]), 0.0f);
        ((__half2*)agg)[((size_t)n << 5) + fl] = __floats2half2_rn(ox, oy);
    }
}

// ---------- LSTM + FC fused: f16 MFMA, double-buffered A (1 barrier/step),
//            early seq prefetch; FC head + softmax in epilogue ----------
__global__ __launch_bounds__(512, 2) void k_lstm(const unsigned short* __restrict__ seq,  // relu'd f16 (NN x 64)
                                                 const unsigned short* __restrict__ Bus,
                                                 const float* __restrict__ biasb,
                                                 const float* __restrict__ fw1,
                                                 const float* __restrict__ fb1,
                                                 const float* __restrict__ fw2,
                                                 const float* __restrict__ fb2,
                                                 float* __restrict__ out) {
    __shared__ unsigned short Aus[2][6 * 512];   // double-buffered A panel
    __shared__ float fw1s[128 * 64];             // FC W1 (32KB)
    __shared__ float hsm[16][128];               // final h
    __shared__ float hid2[16][64];               // FC hidden
    int tid = threadIdx.x;
    int lane = tid & 63;
    int w = tid >> 6;
    int b0 = blockIdx.x * LROWS;

    int u = w * 16 + (lane & 15);
    int rbase = (lane >> 4) * 4;
    float bI = biasb[u], bF = biasb[128 + u], bG = biasb[256 + u], bO = biasb[384 + u];
    float cst[4] = {0.0f, 0.0f, 0.0f, 0.0f};

    short8 Bf[24];   // [ks*4+g]
    #pragma unroll
    for (int ks = 0; ks < 6; ++ks) {
        #pragma unroll
        for (int g = 0; g < 4; ++g) {
            int ci = ks * 32 + 8 * g + w;
            Bf[ks * 4 + g] = *(const short8*)&Bus[(size_t)ci * 512 + lane * 8];
        }
    }

    // constant staging indices (this thread stages seq elements k0, k0+1 of row srow)
    int i0 = tid * 2;
    int srow = i0 >> 6, sk0 = i0 & 63;
    int ksA = sk0 >> 5, krA = sk0 & 31;
    int idxA = ksA * 512 + (((krA >> 3) << 4) + srow) * 8 + (krA & 7);
    int ksB = (sk0 + 1) >> 5, krB = (sk0 + 1) & 31;
    int idxB = ksB * 512 + (((krB >> 3) << 4) + srow) * 8 + (krB & 7);
    const unsigned short* seqrow = seq + (size_t)(b0 + srow) * NT * 64 + sk0;
    // constant h-write base for this thread's unit u
    int kh = 64 + u;
    int hbase = (kh >> 5) * 512 + (((kh & 31) >> 3) << 4) * 8 + (kh & 7);

    // stage fw1 -> LDS (once)
    for (int i = tid; i < 128 * 64; i += 512) fw1s[i] = fw1[i];

    // zero h region of buf0 (chunks 2..5), stage seq t=0 into buf0
    for (int i = tid; i < 1024; i += 512) ((unsigned int*)Aus[0])[512 + i] = 0;
    {
        unsigned v = *(const unsigned*)seqrow;
        Aus[0][idxA] = (unsigned short)v;
        Aus[0][idxB] = (unsigned short)(v >> 16);
    }
    __syncthreads();

    int p = 0;
    for (int t = 0; t < NT; ++t) {
        // prefetch seq(t+1) BEFORE compute: HBM latency hides under MFMA phase
        unsigned vnext = 0u;
        if (t < NT - 1) vnext = *(const unsigned*)(seqrow + (size_t)(t + 1) * 64);

        f32x4 acc[4];
        #pragma unroll
        for (int g = 0; g < 4; ++g) acc[g] = (f32x4){0.f, 0.f, 0.f, 0.f};
        #pragma unroll
        for (int ks = 0; ks < 6; ++ks) {
            short8 ah = *(const short8*)&Aus[p][ks * 512 + lane * 8];
            #pragma unroll
            for (int g = 0; g < 4; ++g)
                acc[g] = __builtin_amdgcn_mfma_f32_16x16x32_f16(ah, Bf[ks * 4 + g], acc[g], 0, 0, 0);
        }
        // writes go to buf p^1 (no conflict with in-flight reads of buf p)
        if (t == NT - 1) {
            #pragma unroll
            for (int q = 0; q < 4; ++q) {
                float nc = fsigm(acc[1][q] + bF) * cst[q]
                         + fsigm(acc[0][q] + bI) * ftanh(acc[2][q] + bG);
                cst[q] = nc;
                hsm[rbase + q][u] = fsigm(acc[3][q] + bO) * ftanh(nc);
            }
        } else {
            #pragma unroll
            for (int q = 0; q < 4; ++q) {
                float nc = fsigm(acc[1][q] + bF) * cst[q]
                         + fsigm(acc[0][q] + bI) * ftanh(acc[2][q] + bG);
                cst[q] = nc;
                float hv = fsigm(acc[3][q] + bO) * ftanh(nc);
                Aus[p ^ 1][hbase + (rbase + q) * 8] = hbits(hv);
            }
            Aus[p ^ 1][idxA] = (unsigned short)vnext;
            Aus[p ^ 1][idxB] = (unsigned short)(vnext >> 16);
        }
        __syncthreads();   // buf p^1 staged; hsm ready at last step
        p ^= 1;
    }

    // ---- FC head: row = tid>>5 (0..15), features f0, f0+1 ----
    {
        int row = tid >> 5;
        int f0 = (tid & 31) * 2;
        float a0 = fb1[f0], a1 = fb1[f0 + 1];
        #pragma unroll 8
        for (int k = 0; k < 128; ++k) {
            float hk = hsm[row][k];
            a0 = fmaf(hk, fw1s[k * 64 + f0], a0);
            a1 = fmaf(hk, fw1s[k * 64 + f0 + 1], a1);
        }
        hid2[row][f0] = fmaxf(a0, 0.0f);
        hid2[row][f0 + 1] = fmaxf(a1, 0.0f);
    }
    __syncthreads();
    if (tid < 16) {
        float lg[3];
        #pragma unroll
        for (int l = 0; l < 3; ++l) {
            float a = fb2[l];
            for (int j = 0; j < 64; ++j) a = fmaf(hid2[tid][j], fw2[j * 3 + l], a);
            lg[l] = a;
        }
        float m = fmaxf(lg[0], fmaxf(lg[1], lg[2]));
        float e0 = expf(lg[0] - m), e1 = expf(lg[1] - m), e2 = expf(lg[2] - m);
        float s = 1.0f / (e0 + e1 + e2);
        size_t ob = (size_t)(b0 + tid) * 3;
        out[ob + 0] = e0 * s;
        out[ob + 1] = e1 * s;
        out[ob + 2] = e2 * s;
    }
}

extern "C" void kernel_launch(void* const* d_in, const int* in_sizes, int n_in,
                              void* d_out, int out_size, void* d_ws, size_t ws_size,
                              hipStream_t stream) {
    const float* x    = (const float*)d_in[0];
    const float* ea   = (const float*)d_in[1];
    const float* W1   = (const float*)d_in[2];
    const float* b1   = (const float*)d_in[3];
    const float* W2   = (const float*)d_in[4];
    const float* b2   = (const float*)d_in[5];
    const float* W_ih = (const float*)d_in[6];
    const float* W_hh = (const float*)d_in[7];
    const float* b_ih = (const float*)d_in[8];
    const float* b_hh = (const float*)d_in[9];
    const float* fw1  = (const float*)d_in[10];
    const float* fb1  = (const float*)d_in[11];
    const float* fw2  = (const float*)d_in[12];
    const float* fb2  = (const float*)d_in[13];
    const int*   ei   = (const int*)d_in[14];
    float* out = (float*)d_out;

    float* ws    = (float*)d_ws;
    float* dinv  = ws;                          // NN
    float* bufA  = dinv + NN;                   // NN*64 fp32 region (reused: binned, fp16 linp)
    float* bufB  = bufA + NN * 64;              // NN*64 region (fp16 agg2, LSTM input)
    unsigned short* Bus = (unsigned short*)(bufB + NN * 64);   // 98304 ushort (f16 frags)
    float* biasb = bufB + NN * 64 + 98304 / 2;  // 512
    int*   bcur  = (int*)(biasb + 512);         // 256
    int*   offS  = bcur + 256;                  // NN
    int*   offE  = offS + NN;                   // NN
    unsigned* edata = (unsigned*)(offE + NN);   // NBKT*BSTRIDE * 4B (strided buckets)
    __half* aggx = (__half*)(edata + NBKT * BSTRIDE);  // NN*16 fp16 (layer-1 agg)
    __half* xh   = aggx + NN * 16;              // NN*16 fp16 (L2-resident gather operand)
    unsigned short* W1f = (unsigned short*)(xh + NN * 16);   // 2048 ushort
    unsigned short* W2f = W1f + 2048;                        // 4096 ushort
    unsigned* binnedA = (unsigned*)bufA;        // NBKT*BSTRIDE u32 (5.12MB, dead after k_csr)
    unsigned short* binnedW = (unsigned short*)(binnedA + NBKT * BSTRIDE);  // 2.56MB
    __half* linp  = (__half*)bufA;              // NN*64 fp16 (after binned is dead)
    __half* aggB  = (__half*)bufB;              // NN*64 fp16 (relu'd layer-2 out)

    // weight fragments (LSTM + GCN) + bcur zero, no upstream deps -> first
    k_wfrag<<<386, 256, 0, stream>>>(W_ih, W_hh, b_ih, b_hh, W1, W2, Bus, biasb, W1f, W2f, bcur);

    // ---- scan-free CSR build: strided buckets, direct atomic reservation ----
    k_bin<<<NBKT, 256, 0, stream>>>(ei, ea, bcur, binnedA, binnedW);
    k_csr<<<NBKT, 256, 0, stream>>>(binnedA, binnedW, bcur, x, edata, offS, offE, dinv, xh);

    // GCN layer 1 via commuted aggregation (L2-resident 16-feat operand)
    k_gather16<<<16000, 256, 0, stream>>>(xh, edata, offS, offE, dinv, aggx);

    // deferred W1 + layer-2 lin, fused, MFMA
    k_lin2f<<<1000, 256, 0, stream>>>(aggx, W1f, b1, W2f, dinv, linp);

    // GCN layer 2 gather (single pass, 64-feat fp16 rows; relu'd f16 output)
    k_gather<<<16000, 256, 0, stream>>>(linp, edata, offS, offE, dinv, b2, aggB);

    // LSTM + FC head fused (seq already relu'd f16; staging is a bit copy)
    k_lstm<<<250, 512, 0, stream>>>((const unsigned short*)aggB, Bus, biasb,
                                    fw1, fb1, fw2, fb2, out);
}

// Round 24
// 130.217 us; speedup vs baseline: 1.0364x; 1.0364x over previous
//
#include <hip/hip_runtime.h>
#include <hip/hip_bf16.h>
#include <hip/hip_fp16.h>
#include <math.h>

#define NN 64000      // nodes
#define NE 1024000    // edges
#define NB 4000       // sequences
#define NT 16         // timesteps
#define LROWS 16      // sequences per LSTM block
#define NBKT 250      // coarse buckets (c>>8), NN/256
#define BSTRIDE 5120  // fixed per-bucket slot region (mean 4096, sigma 64 -> 16-sigma margin)

typedef __attribute__((ext_vector_type(8))) short short8;
typedef __attribute__((ext_vector_type(4))) float f32x4;

// fast sigmoid/tanh: v_exp + v_rcp (exact at +-inf limits)
__device__ __forceinline__ float fsigm(float x) {
    return __builtin_amdgcn_rcpf(1.0f + __expf(-x));
}
__device__ __forceinline__ float ftanh(float x) {
    return 1.0f - 2.0f * __builtin_amdgcn_rcpf(1.0f + __expf(2.0f * x));
}
__device__ __forceinline__ unsigned short hbits(float v) {
    __half h = __float2half(v);
    return reinterpret_cast<unsigned short&>(h);
}
__device__ __forceinline__ float hval(unsigned short b) {
    __half h;
    reinterpret_cast<unsigned short&>(h) = b;
    return __half2float(h);
}

// ---------- P1: bin edges by bucket via LDS sort; direct atomic slot reservation ----------
// record: x = r | (c&255)<<16 | bucket<<24 ; y = raw ew bits (fp32, exact dinv)
// bucket b's region: binned[b*BSTRIDE .. b*BSTRIDE + cnt_b); cnt accumulated in bcur[b]
__global__ __launch_bounds__(256) void k_bin(const int* __restrict__ ei,
                                             const float* __restrict__ ew,
                                             int* __restrict__ bcur,
                                             uint2* __restrict__ binned) {
    __shared__ uint2 stage[4096];
    __shared__ int sm[256];
    __shared__ int lcur[256], ladj[256];
    int tid = threadIdx.x;
    sm[tid] = 0;
    __syncthreads();
    int base = blockIdx.x * 4096;
    int cs[16];
    #pragma unroll
    for (int j = 0; j < 16; ++j) {
        cs[j] = ei[NE + base + j * 256 + tid];
        atomicAdd(&sm[cs[j] >> 8], 1);
    }
    __syncthreads();
    int v = sm[tid];
    #pragma unroll
    for (int d = 1; d < 256; d <<= 1) {
        int t = (tid >= d) ? sm[tid - d] : 0;
        __syncthreads();
        sm[tid] += t;
        __syncthreads();
    }
    int ex = sm[tid] - v;
    lcur[tid] = ex;
    if (tid < NBKT) ladj[tid] = tid * BSTRIDE + atomicAdd(&bcur[tid], v) - ex;
    __syncthreads();
    #pragma unroll
    for (int j = 0; j < 16; ++j) {
        int e = base + j * 256 + tid;
        int c = cs[j];
        int b = c >> 8;
        unsigned r = (unsigned)ei[e];
        float wv = ew[e];
        int slot = atomicAdd(&lcur[b], 1);
        stage[slot] = make_uint2(r | ((unsigned)(c & 255) << 16) | ((unsigned)b << 24),
                                 __float_as_uint(wv));
    }
    __syncthreads();
    #pragma unroll
    for (int j = 0; j < 16; ++j) {
        int i = j * 256 + tid;
        uint2 rec = stage[i];
        int b = rec.x >> 24;
        binned[ladj[b] + i] = rec;
    }
}

// ---------- P2: per-bucket final CSR sort + offS/offE + dinv + fused xh ----------
// edata packed 4B: r (low16) | f16(w) (high16); strided bucket regions
__global__ __launch_bounds__(256) void k_csr(const uint2* __restrict__ binned,
                                             const int* __restrict__ bcur,
                                             const float* __restrict__ x,
                                             unsigned* __restrict__ edata,
                                             int* __restrict__ offS,
                                             int* __restrict__ offE,
                                             float* __restrict__ dinv,
                                             __half* __restrict__ xh) {
    __shared__ int cnt[256];
    __shared__ float sumw[256];
    __shared__ int lcur[256];
    __shared__ int sm[256];
    int tid = threadIdx.x;
    int b = blockIdx.x;
    int s = b * BSTRIDE;
    int e1 = s + bcur[b];
    cnt[tid] = 0;
    sumw[tid] = 0.0f;
    __syncthreads();
    for (int i = s + tid; i < e1; i += 256) {
        uint2 rec = binned[i];
        int nl = (rec.x >> 16) & 255;
        atomicAdd(&cnt[nl], 1);
        atomicAdd(&sumw[nl], __uint_as_float(rec.y));
    }
    __syncthreads();
    int v = cnt[tid];
    sm[tid] = v;
    __syncthreads();
    #pragma unroll
    for (int d = 1; d < 256; d <<= 1) {
        int t = (tid >= d) ? sm[tid - d] : 0;
        __syncthreads();
        sm[tid] += t;
        __syncthreads();
    }
    int ex = sm[tid] - v;
    offS[b * 256 + tid] = s + ex;
    offE[b * 256 + tid] = s + ex + v;
    float dv = rsqrtf(1.0f + sumw[tid]);
    dinv[b * 256 + tid] = dv;
    sumw[tid] = dv;           // stash for xh loop
    lcur[tid] = ex;
    __syncthreads();
    for (int i = s + tid; i < e1; i += 256) {
        uint2 rec = binned[i];
        int nl = (rec.x >> 16) & 255;
        int p = atomicAdd(&lcur[nl], 1);
        edata[s + p] = (rec.x & 0xFFFFu) |
                       ((unsigned)hbits(__uint_as_float(rec.y)) << 16);
    }
    // fused xh = x * dinv for this block's 256 nodes
    size_t nb = (size_t)b * 4096;
    for (int i = tid; i < 4096; i += 256) {
        xh[nb + i] = __float2half(x[nb + i] * sumw[i >> 4]);
    }
}

// ---------- gather on 16-feature xh: aggx[n] = f16( dinv[n]*(xh[n] + sum ew*xh[r]) ) ----------
__global__ __launch_bounds__(256) void k_gather16(const __half* __restrict__ xh,
                                                  const unsigned* __restrict__ edata,
                                                  const int* __restrict__ offS,
                                                  const int* __restrict__ offE,
                                                  const float* __restrict__ dinv,
                                                  __half* __restrict__ aggx) {
    int tid = threadIdx.x;
    int lane = tid & 63;
    int wv = tid >> 6;
    int n = blockIdx.x * 4 + wv;
    int g = lane >> 3;        // edge group 0..7
    int fl = lane & 7;        // feature-pair 0..7
    const __half2* xh2 = (const __half2*)xh;   // row stride 8 half2
    float2 acc = make_float2(0.0f, 0.0f);
    if (g == 0) acc = __half22float2(xh2[((size_t)n << 3) + fl]);   // self term
    int s = offS[n], e1 = offE[n];
    int e = s + g;
    for (; e + 8 < e1; e += 16) {
        unsigned d0 = edata[e];
        unsigned d1 = edata[e + 8];
        float2 l0 = __half22float2(xh2[((size_t)(d0 & 0xFFFFu) << 3) + fl]);
        float2 l1 = __half22float2(xh2[((size_t)(d1 & 0xFFFFu) << 3) + fl]);
        float w0 = hval((unsigned short)(d0 >> 16));
        float w1 = hval((unsigned short)(d1 >> 16));
        acc.x = fmaf(w0, l0.x, acc.x); acc.y = fmaf(w0, l0.y, acc.y);
        acc.x = fmaf(w1, l1.x, acc.x); acc.y = fmaf(w1, l1.y, acc.y);
    }
    if (e < e1) {
        unsigned d0 = edata[e];
        float2 l0 = __half22float2(xh2[((size_t)(d0 & 0xFFFFu) << 3) + fl]);
        float w0 = hval((unsigned short)(d0 >> 16));
        acc.x = fmaf(w0, l0.x, acc.x);
        acc.y = fmaf(w0, l0.y, acc.y);
    }
    acc.x += __shfl_xor(acc.x, 8, 64);
    acc.y += __shfl_xor(acc.y, 8, 64);
    acc.x += __shfl_xor(acc.x, 16, 64);
    acc.y += __shfl_xor(acc.y, 16, 64);
    acc.x += __shfl_xor(acc.x, 32, 64);
    acc.y += __shfl_xor(acc.y, 32, 64);
    if (g == 0) {
        float dn = dinv[n];
        ((__half2*)aggx)[((size_t)n << 3) + fl] = __floats2half2_rn(dn * acc.x, dn * acc.y);
    }
}

// ---------- fused weight fragments + bcur zero ----------
// blocks 0..383: LSTM f16 frags; block 384: GCN frags; block 385: zero bcur
__global__ __launch_bounds__(256) void k_wfrag(const float* __restrict__ W_ih,
                                               const float* __restrict__ W_hh,
                                               const float* __restrict__ b_ih,
                                               const float* __restrict__ b_hh,
                                               const float* __restrict__ W1,
                                               const float* __restrict__ W2,
                                               unsigned short* __restrict__ Bus,
                                               float* __restrict__ biasb,
                                               unsigned short* __restrict__ W1f,
                                               unsigned short* __restrict__ W2f,
                                               int* __restrict__ bcur) {
    int tid = threadIdx.x;
    int blk = blockIdx.x;
    if (blk < 384) {
        int i = blk * 256 + tid;
        if (i < 192 * 512) {
            int j = i & 7;
            int l = (i >> 3) & 63;
            int ci = i >> 9;
            int ntg = ci & 31;
            int ks = ci >> 5;
            int col = ntg * 16 + (l & 15);
            int k = ks * 32 + ((l >> 4) << 3) + j;
            float w = (k < 64) ? W_ih[col * 64 + k] : W_hh[col * 128 + (k - 64)];
            Bus[i] = hbits(w);
        }
        if (i < 512) biasb[i] = b_ih[i] + b_hh[i];
    } else if (blk == 384) {
        for (int i = tid; i < 6144; i += 256) {
            if (i < 2048) {
                int j = i & 7, l = (i >> 3) & 63, nt = i >> 9;
                int n = nt * 16 + (l & 15);
                int k = ((l >> 4) << 3) + j;          // 0..31
                W1f[i] = (k < 16) ? hbits(W1[k * 64 + n]) : (unsigned short)0;
            } else {
                int i2 = i - 2048;
                int j = i2 & 7, l = (i2 >> 3) & 63, ci = i2 >> 9;
                int nt = ci & 3, ks = ci >> 2;
                int n = nt * 16 + (l & 15);
                int k = ks * 32 + ((l >> 4) << 3) + j;
                W2f[i2] = hbits(W2[k * 64 + n]);
            }
        }
    } else {
        bcur[tid] = 0;
    }
}

// ---------- fused deferred-W1 + layer-2 lin via MFMA ----------
// 64 rows/block, 4 waves. hid = relu(aggx@W1 + b1); linp2 = (hid@W2)*dinv -> fp16
__global__ __launch_bounds__(256) void k_lin2f(const __half* __restrict__ aggx,
                                               const unsigned short* __restrict__ W1f,
                                               const float* __restrict__ b1,
                                               const unsigned short* __restrict__ W2f,
                                               const float* __restrict__ dinv,
                                               __half* __restrict__ linp2) {
    __shared__ unsigned short Ax[4][512];      // GEMM1 A-frags, per wave
    __shared__ unsigned short Hd[4][2][512];   // hid A-frags (K=64 -> 2 chunks), per wave
    __shared__ unsigned short Ot[64 * 64];     // output staging
    int tid = threadIdx.x;
    int lane = tid & 63;
    int w = tid >> 6;
    int n0 = blockIdx.x * 64;

    // B fragments -> registers
    short8 B1[4], B2[8];
    #pragma unroll
    for (int nt = 0; nt < 4; ++nt) B1[nt] = *(const short8*)&W1f[nt * 512 + lane * 8];
    #pragma unroll
    for (int ci = 0; ci < 8; ++ci) B2[ci] = *(const short8*)&W2f[ci * 512 + lane * 8];

    // zero the k>=16 half of each Ax chunk
    {
        int idx = tid;
        ((unsigned int*)Ax)[(idx >> 7) * 256 + 128 + (idx & 127)] = 0;
        idx += 256;
        ((unsigned int*)Ax)[(idx >> 7) * 256 + 128 + (idx & 127)] = 0;
    }
    // stage aggx (f16 bits) -> A-layout: row=tid>>2, k0=(tid&3)*4 (pure bit copy)
    {
        int row = tid >> 2, k0 = (tid & 3) * 4;
        uint2 bits = *(const uint2*)(aggx + (size_t)(n0 + row) * 16 + k0);
        unsigned short hv[4] = {(unsigned short)(bits.x & 0xFFFF), (unsigned short)(bits.x >> 16),
                                (unsigned short)(bits.y & 0xFFFF), (unsigned short)(bits.y >> 16)};
        int wq = row >> 4, m = row & 15;
        #pragma unroll
        for (int d = 0; d < 4; ++d) {
            int k = k0 + d;
            Ax[wq][(((k >> 3) << 4) + m) * 8 + (k & 7)] = hv[d];
        }
    }
    __syncthreads();

    // GEMM1: [16x32(pad)] @ W1 -> 4 N-tiles
    short8 a = *(const short8*)&Ax[w][lane * 8];
    f32x4 acc[4];
    #pragma unroll
    for (int nt = 0; nt < 4; ++nt) acc[nt] = (f32x4){0.f, 0.f, 0.f, 0.f};
    #pragma unroll
    for (int nt = 0; nt < 4; ++nt)
        acc[nt] = __builtin_amdgcn_mfma_f32_16x16x32_f16(a, B1[nt], acc[nt], 0, 0, 0);

    // epilogue 1: relu(acc + b1[col]) -> Hd in GEMM2 A-layout
    int rb = (lane >> 4) * 4;
    #pragma unroll
    for (int nt = 0; nt < 4; ++nt) {
        int col = nt * 16 + (lane & 15);
        float bc = b1[col];
        #pragma unroll
        for (int q = 0; q < 4; ++q) {
            float hv = fmaxf(acc[nt][q] + bc, 0.0f);
            int row = rb + q;
            Hd[w][col >> 5][((((col & 31) >> 3) << 4) + row) * 8 + (col & 7)] = hbits(hv);
        }
    }
    short8 a0 = *(const short8*)&Hd[w][0][lane * 8];
    short8 a1 = *(const short8*)&Hd[w][1][lane * 8];
    f32x4 c2[4];
    #pragma unroll
    for (int nt = 0; nt < 4; ++nt) c2[nt] = (f32x4){0.f, 0.f, 0.f, 0.f};
    #pragma unroll
    for (int nt = 0; nt < 4; ++nt)
        c2[nt] = __builtin_amdgcn_mfma_f32_16x16x32_f16(a0, B2[nt], c2[nt], 0, 0, 0);
    #pragma unroll
    for (int nt = 0; nt < 4; ++nt)
        c2[nt] = __builtin_amdgcn_mfma_f32_16x16x32_f16(a1, B2[4 + nt], c2[nt], 0, 0, 0);

    // epilogue 2: * dinv[row] -> Ot
    float dv[4];
    #pragma unroll
    for (int q = 0; q < 4; ++q) dv[q] = dinv[n0 + w * 16 + rb + q];
    #pragma unroll
    for (int nt = 0; nt < 4; ++nt) {
        int col = nt * 16 + (lane & 15);
        #pragma unroll
        for (int q = 0; q < 4; ++q) {
            Ot[(w * 16 + rb + q) * 64 + col] = hbits(c2[nt][q] * dv[q]);
        }
    }
    __syncthreads();
    {
        int row = tid >> 2, c0 = (tid & 3) * 16;
        short8 v0 = *(const short8*)&Ot[row * 64 + c0];
        short8 v1 = *(const short8*)&Ot[row * 64 + c0 + 8];
        *(short8*)&linp2[(size_t)(n0 + row) * 64 + c0] = v0;
        *(short8*)&linp2[(size_t)(n0 + row) * 64 + c0 + 8] = v1;
    }
}

// ---------- CSR gather, split-wave half2 (layer 2, 64 features) ----------
// output fp16 with relu pre-applied (LSTM staging becomes a bit copy)
__global__ __launch_bounds__(256) void k_gather(const __half* __restrict__ linp,
                                                const unsigned* __restrict__ edata,
                                                const int* __restrict__ offS,
                                                const int* __restrict__ offE,
                                                const float* __restrict__ dinv,
                                                const float* __restrict__ bvec,
                                                __half* __restrict__ agg) {
    int tid = threadIdx.x;
    int lane = tid & 63;
    int wv = tid >> 6;
    int n = blockIdx.x * 4 + wv;
    int hf = lane >> 5;
    int fl = lane & 31;                       // feature-pair index
    const __half2* lp2 = (const __half2*)linp;
    float2 acc = make_float2(0.0f, 0.0f);
    if (hf == 0) {
        acc = __half22float2(lp2[((size_t)n << 5) + fl]);   // self term (once)
    }
    int s = offS[n], e1 = offE[n];
    int e = s + hf;
    for (; e + 6 < e1; e += 8) {
        unsigned d0 = edata[e];
        unsigned d1 = edata[e + 2];
        unsigned d2 = edata[e + 4];
        unsigned d3 = edata[e + 6];
        float2 l0 = __half22float2(lp2[((size_t)(d0 & 0xFFFFu) << 5) + fl]);
        float2 l1 = __half22float2(lp2[((size_t)(d1 & 0xFFFFu) << 5) + fl]);
        float2 l2 = __half22float2(lp2[((size_t)(d2 & 0xFFFFu) << 5) + fl]);
        float2 l3 = __half22float2(lp2[((size_t)(d3 & 0xFFFFu) << 5) + fl]);
        float w0 = hval((unsigned short)(d0 >> 16));
        float w1 = hval((unsigned short)(d1 >> 16));
        float w2 = hval((unsigned short)(d2 >> 16));
        float w3 = hval((unsigned short)(d3 >> 16));
        acc.x = fmaf(w0, l0.x, acc.x); acc.y = fmaf(w0, l0.y, acc.y);
        acc.x = fmaf(w1, l1.x, acc.x); acc.y = fmaf(w1, l1.y, acc.y);
        acc.x = fmaf(w2, l2.x, acc.x); acc.y = fmaf(w2, l2.y, acc.y);
        acc.x = fmaf(w3, l3.x, acc.x); acc.y = fmaf(w3, l3.y, acc.y);
    }
    for (; e < e1; e += 2) {
        unsigned d0 = edata[e];
        float2 l0 = __half22float2(lp2[((size_t)(d0 & 0xFFFFu) << 5) + fl]);
        float w0 = hval((unsigned short)(d0 >> 16));
        acc.x = fmaf(w0, l0.x, acc.x);
        acc.y = fmaf(w0, l0.y, acc.y);
    }
    acc.x += __shfl_xor(acc.x, 32, 64);
    acc.y += __shfl_xor(acc.y, 32, 64);
    if (hf == 0) {
        float dn = dinv[n];
        float ox = fmaxf(fmaf(dn, acc.x, bvec[fl * 2]), 0.0f);
        float oy = fmaxf(fmaf(dn, acc.y, bvec[fl * 2 + 1]), 0.0f);
        ((__half2*)agg)[((size_t)n << 5) + fl] = __floats2half2_rn(ox, oy);
    }
}

// ---------- LSTM + FC fused: f16 MFMA, double-buffered A (1 barrier/step),
//            FC head + softmax in epilogue ----------
__global__ __launch_bounds__(512, 2) void k_lstm(const unsigned short* __restrict__ seq,  // relu'd f16 (NN x 64)
                                                 const unsigned short* __restrict__ Bus,
                                                 const float* __restrict__ biasb,
                                                 const float* __restrict__ fw1,
                                                 const float* __restrict__ fb1,
                                                 const float* __restrict__ fw2,
                                                 const float* __restrict__ fb2,
                                                 float* __restrict__ out) {
    __shared__ unsigned short Aus[2][6 * 512];   // double-buffered A panel
    __shared__ float fw1s[128 * 64];             // FC W1 (32KB)
    __shared__ float hsm[16][128];               // final h
    __shared__ float hid2[16][64];               // FC hidden
    int tid = threadIdx.x;
    int lane = tid & 63;
    int w = tid >> 6;
    int b0 = blockIdx.x * LROWS;

    int u = w * 16 + (lane & 15);
    int rbase = (lane >> 4) * 4;
    float bI = biasb[u], bF = biasb[128 + u], bG = biasb[256 + u], bO = biasb[384 + u];
    float cst[4] = {0.0f, 0.0f, 0.0f, 0.0f};

    short8 Bf[24];   // [ks*4+g]
    #pragma unroll
    for (int ks = 0; ks < 6; ++ks) {
        #pragma unroll
        for (int g = 0; g < 4; ++g) {
            int ci = ks * 32 + 8 * g + w;
            Bf[ks * 4 + g] = *(const short8*)&Bus[(size_t)ci * 512 + lane * 8];
        }
    }

    // stage fw1 -> LDS (once)
    for (int i = tid; i < 128 * 64; i += 512) fw1s[i] = fw1[i];

    // zero h region of buf0 (chunks 2..5), stage seq t=0 into buf0
    for (int i = tid; i < 1024; i += 512) ((unsigned int*)Aus[0])[512 + i] = 0;
    {
        int i0 = tid * 2;
        int row = i0 >> 6, k0 = i0 & 63;
        unsigned v = *(const unsigned*)&seq[((size_t)(b0 + row) * NT + 0) * 64 + k0];
        int ks = k0 >> 5, kr = k0 & 31;
        Aus[0][ks * 512 + (((kr >> 3) << 4) + row) * 8 + (kr & 7)] = (unsigned short)v;
        kr = (k0 + 1) & 31; ks = (k0 + 1) >> 5;
        Aus[0][ks * 512 + (((kr >> 3) << 4) + row) * 8 + (kr & 7)] = (unsigned short)(v >> 16);
    }
    __syncthreads();

    int p = 0;
    for (int t = 0; t < NT; ++t) {
        f32x4 acc[4];
        #pragma unroll
        for (int g = 0; g < 4; ++g) acc[g] = (f32x4){0.f, 0.f, 0.f, 0.f};
        #pragma unroll
        for (int ks = 0; ks < 6; ++ks) {
            short8 ah = *(const short8*)&Aus[p][ks * 512 + lane * 8];
            #pragma unroll
            for (int g = 0; g < 4; ++g)
                acc[g] = __builtin_amdgcn_mfma_f32_16x16x32_f16(ah, Bf[ks * 4 + g], acc[g], 0, 0, 0);
        }
        // writes go to buf p^1 (no conflict with in-flight reads of buf p)
        if (t == NT - 1) {
            #pragma unroll
            for (int q = 0; q < 4; ++q) {
                float nc = fsigm(acc[1][q] + bF) * cst[q]
                         + fsigm(acc[0][q] + bI) * ftanh(acc[2][q] + bG);
                cst[q] = nc;
                hsm[rbase + q][u] = fsigm(acc[3][q] + bO) * ftanh(nc);
            }
        } else {
            int kh = 64 + u;
            int ksh = kh >> 5, krh = kh & 31;
            int hbase = ksh * 512 + ((krh >> 3) << 4) * 8 + (krh & 7);
            #pragma unroll
            for (int q = 0; q < 4; ++q) {
                float nc = fsigm(acc[1][q] + bF) * cst[q]
                         + fsigm(acc[0][q] + bI) * ftanh(acc[2][q] + bG);
                cst[q] = nc;
                float hv = fsigm(acc[3][q] + bO) * ftanh(nc);
                Aus[p ^ 1][hbase + (rbase + q) * 8] = hbits(hv);
            }
            {
                int i0 = tid * 2;
                int row = i0 >> 6, k0 = i0 & 63;
                unsigned v = *(const unsigned*)&seq[((size_t)(b0 + row) * NT + (t + 1)) * 64 + k0];
                int ks = k0 >> 5, kr = k0 & 31;
                Aus[p ^ 1][ks * 512 + (((kr >> 3) << 4) + row) * 8 + (kr & 7)] = (unsigned short)v;
                kr = (k0 + 1) & 31; ks = (k0 + 1) >> 5;
                Aus[p ^ 1][ks * 512 + (((kr >> 3) << 4) + row) * 8 + (kr & 7)] = (unsigned short)(v >> 16);
            }
        }
        __syncthreads();   // buf p^1 staged; hsm ready at last step
        p ^= 1;
    }

    // ---- FC head: row = tid>>5 (0..15), features f0, f0+1 ----
    {
        int row = tid >> 5;
        int f0 = (tid & 31) * 2;
        float a0 = fb1[f0], a1 = fb1[f0 + 1];
        #pragma unroll 8
        for (int k = 0; k < 128; ++k) {
            float hk = hsm[row][k];
            a0 = fmaf(hk, fw1s[k * 64 + f0], a0);
            a1 = fmaf(hk, fw1s[k * 64 + f0 + 1], a1);
        }
        hid2[row][f0] = fmaxf(a0, 0.0f);
        hid2[row][f0 + 1] = fmaxf(a1, 0.0f);
    }
    __syncthreads();
    if (tid < 16) {
        float lg[3];
        #pragma unroll
        for (int l = 0; l < 3; ++l) {
            float a = fb2[l];
            for (int j = 0; j < 64; ++j) a = fmaf(hid2[tid][j], fw2[j * 3 + l], a);
            lg[l] = a;
        }
        float m = fmaxf(lg[0], fmaxf(lg[1], lg[2]));
        float e0 = expf(lg[0] - m), e1 = expf(lg[1] - m), e2 = expf(lg[2] - m);
        float s = 1.0f / (e0 + e1 + e2);
        size_t ob = (size_t)(b0 + tid) * 3;
        out[ob + 0] = e0 * s;
        out[ob + 1] = e1 * s;
        out[ob + 2] = e2 * s;
    }
}

extern "C" void kernel_launch(void* const* d_in, const int* in_sizes, int n_in,
                              void* d_out, int out_size, void* d_ws, size_t ws_size,
                              hipStream_t stream) {
    const float* x    = (const float*)d_in[0];
    const float* ea   = (const float*)d_in[1];
    const float* W1   = (const float*)d_in[2];
    const float* b1   = (const float*)d_in[3];
    const float* W2   = (const float*)d_in[4];
    const float* b2   = (const float*)d_in[5];
    const float* W_ih = (const float*)d_in[6];
    const float* W_hh = (const float*)d_in[7];
    const float* b_ih = (const float*)d_in[8];
    const float* b_hh = (const float*)d_in[9];
    const float* fw1  = (const float*)d_in[10];
    const float* fb1  = (const float*)d_in[11];
    const float* fw2  = (const float*)d_in[12];
    const float* fb2  = (const float*)d_in[13];
    const int*   ei   = (const int*)d_in[14];
    float* out = (float*)d_out;

    float* ws    = (float*)d_ws;
    float* dinv  = ws;                          // NN
    float* bufA  = dinv + NN;                   // NN*64 fp32 region (reused: binned, fp16 linp)
    float* bufB  = bufA + NN * 64;              // NN*64 region (fp16 agg2, LSTM input)
    unsigned short* Bus = (unsigned short*)(bufB + NN * 64);   // 98304 ushort (f16 frags)
    float* biasb = bufB + NN * 64 + 98304 / 2;  // 512
    int*   bcur  = (int*)(biasb + 512);         // 256
    int*   offS  = bcur + 256;                  // NN
    int*   offE  = offS + NN;                   // NN
    unsigned* edata = (unsigned*)(offE + NN);   // NBKT*BSTRIDE * 4B (strided buckets)
    __half* aggx = (__half*)(edata + NBKT * BSTRIDE);  // NN*16 fp16 (layer-1 agg)
    __half* xh   = aggx + NN * 16;              // NN*16 fp16 (L2-resident gather operand)
    unsigned short* W1f = (unsigned short*)(xh + NN * 16);   // 2048 ushort
    unsigned short* W2f = W1f + 2048;                        // 4096 ushort
    uint2* binned = (uint2*)bufA;               // NBKT*BSTRIDE * 8B = 10.24MB (dead after k_csr)
    __half* linp  = (__half*)bufA;              // NN*64 fp16 (after binned is dead)
    __half* aggB  = (__half*)bufB;              // NN*64 fp16 (relu'd layer-2 out)

    // weight fragments (LSTM + GCN) + bcur zero, no upstream deps -> first
    k_wfrag<<<386, 256, 0, stream>>>(W_ih, W_hh, b_ih, b_hh, W1, W2, Bus, biasb, W1f, W2f, bcur);

    // ---- scan-free CSR build: strided buckets, direct atomic reservation ----
    k_bin<<<NBKT, 256, 0, stream>>>(ei, ea, bcur, binned);
    k_csr<<<NBKT, 256, 0, stream>>>(binned, bcur, x, edata, offS, offE, dinv, xh);

    // GCN layer 1 via commuted aggregation (L2-resident 16-feat operand)
    k_gather16<<<16000, 256, 0, stream>>>(xh, edata, offS, offE, dinv, aggx);

    // deferred W1 + layer-2 lin, fused, MFMA
    k_lin2f<<<1000, 256, 0, stream>>>(aggx, W1f, b1, W2f, dinv, linp);

    // GCN layer 2 gather (single pass, 64-feat fp16 rows; relu'd f16 output)
    k_gather<<<16000, 256, 0, stream>>>(linp, edata, offS, offE, dinv, b2, aggB);

    // LSTM + FC head fused (seq already relu'd f16; staging is a bit copy)
    k_lstm<<<250, 512, 0, stream>>>((const unsigned short*)aggB, Bus, biasb,
                                    fw1, fb1, fw2, fb2, out);
}